// Round 5
// baseline (858.838 us; speedup 1.0000x reference)
//
#include <hip/hip_runtime.h>
#include <math.h>

#define NN 50000
#define NE 800000
#define CC 64
#define GG 128
#define NB ((NN + 255) / 256)      // 196 node blocks
#define BINS ((NN + 255) / 256)    // 196 bins of 256 target nodes
#define CAPB 4608                  // bin capacity (expect ~4082, +8 sigma)
#define EPB 2048                   // edges per binning block
#define GA ((NE + EPB - 1) / EPB)  // 391 binning blocks

// zero bin counters + stats
__global__ void k_zero(int* bin_cnt, float* stats) {
    int t = blockIdx.x * blockDim.x + threadIdx.x;
    if (t < BINS) bin_cnt[t] = 0;
    if (t < 2 * CC) stats[t] = 0.0f;
}

// bin edges by target>>8; per-block LDS histogram, one global atomic per (block,bin)
__global__ __launch_bounds__(256) void k_binA(const int* __restrict__ ei,
                                              const float* __restrict__ w,
                                              int* __restrict__ bin_cnt,
                                              int2* __restrict__ binbuf) {
    __shared__ int hist[BINS], base[BINS], rank[BINS];
    int t = threadIdx.x;
    for (int b = t; b < BINS; b += 256) { hist[b] = 0; rank[b] = 0; }
    __syncthreads();
    int e0 = blockIdx.x * EPB;
    // phase 1: count
    for (int i = t; i < EPB; i += 256) {
        int e = e0 + i;
        if (e < NE) atomicAdd(&hist[ei[NE + e] >> 8], 1);
    }
    __syncthreads();
    // reserve chunks
    for (int b = t; b < BINS; b += 256)
        if (hist[b] > 0) base[b] = atomicAdd(&bin_cnt[b], hist[b]);
    __syncthreads();
    // phase 2: place
    for (int i = t; i < EPB; i += 256) {
        int e = e0 + i;
        if (e >= NE) continue;
        int r = ei[e], c = ei[NE + e], b = c >> 8;
        int pos = base[b] + atomicAdd(&rank[b], 1);
        if (pos < CAPB)
            binbuf[(size_t)b * CAPB + pos] = make_int2(r | ((c & 255) << 16),
                                                       __float_as_int(w[e]));
    }
}

// per-bin weighted degree (LDS atomics) -> dinv = rsqrt(1 + sum w)
__global__ __launch_bounds__(256) void k_degbin(const int* __restrict__ bin_cnt,
                                                const int2* __restrict__ binbuf,
                                                float* __restrict__ dinv) {
    __shared__ float deg[256];
    int g = blockIdx.x, t = threadIdx.x;
    deg[t] = 1.0f;
    __syncthreads();
    int cnt = min(bin_cnt[g], CAPB);
    const int2* bp = binbuf + (size_t)g * CAPB;
    for (int e = t; e < cnt; e += 256)
        atomicAdd(&deg[bp[e].x >> 16], __int_as_float(bp[e].y));
    __syncthreads();
    int node = g * 256 + t;
    if (node < NN) dinv[node] = rsqrtf(deg[t]);
}

// one block per bin: LDS 256x64 accumulator tile; norm folded on the fly
__global__ __launch_bounds__(1024) void k_hop_bin(const float* __restrict__ in,
                                                  const float* __restrict__ dinv,
                                                  const int* __restrict__ bin_cnt,
                                                  const int2* __restrict__ binbuf,
                                                  float* __restrict__ out) {
    __shared__ float acc[256 * CC];
    __shared__ float dinv_loc[256];
    int g = blockIdx.x;
    int tid = threadIdx.x, wid = tid >> 6, j = tid & 63;
    // init: acc[i,:] = dinv^2 * in[node,:]  (self-loop term)
    for (int i = wid; i < 256; i += 16) {
        int node = g * 256 + i;
        float dl = (node < NN) ? dinv[node] : 0.0f;
        if (j == 0) dinv_loc[i] = dl;
        acc[i * CC + j] = (node < NN) ? dl * dl * in[node * CC + j] : 0.0f;
    }
    __syncthreads();
    int cnt = min(bin_cnt[g], CAPB);
    const int2* bp = binbuf + (size_t)g * CAPB;
    for (int e = wid * 4; e < cnt; e += 64) {
#pragma unroll
        for (int q = 0; q < 4; q++) {
            int idx = e + q;
            if (idx < cnt) {
                int2 rec = bp[idx];
                int src = rec.x & 0xffff, low = rec.x >> 16;
                float nrm = dinv[src] * __int_as_float(rec.y) * dinv_loc[low];
                atomicAdd(&acc[low * CC + j], nrm * in[src * CC + j]);
            }
        }
    }
    __syncthreads();
    for (int i = wid; i < 256; i += 16) {
        int node = g * 256 + i;
        if (node < NN) out[node * CC + j] = acc[i * CC + j];
    }
}

// h @ W^T + b, then PReLU
__global__ __launch_bounds__(256) void k_linear(const float* __restrict__ h,
                                                const float* __restrict__ W,
                                                const float* __restrict__ b,
                                                const float* __restrict__ a,
                                                float* __restrict__ out) {
    __shared__ float Ws[CC * 65];
    __shared__ float hs[4][CC];
    int tid = threadIdx.x;
    for (int t = tid; t < CC * CC; t += 256) {
        int j = t >> 6, k = t & 63;
        Ws[j * 65 + k] = W[t];
    }
    int i0 = blockIdx.x * 4;
    {
        int node = i0 + (tid >> 6), k = tid & 63;
        hs[tid >> 6][k] = (node < NN) ? h[node * CC + k] : 0.0f;
    }
    __syncthreads();
    int node = i0 + (tid >> 6);
    int j = tid & 63;
    if (node >= NN) return;
    float acc = b[j];
    const float* hr = hs[tid >> 6];
#pragma unroll
    for (int k = 0; k < CC; k++) acc += hr[k] * Ws[j * 65 + k];
    float v = acc >= 0.0f ? acc : a[j] * acc;
    out[node * CC + j] = v;
}

// per-channel sum / sumsq over all N rows
__global__ __launch_bounds__(256) void k_stats(const float* __restrict__ h,
                                               float* __restrict__ stats) {
    __shared__ float ssum[4][CC], ssq[4][CC];
    int tid = threadIdx.x, wv = tid >> 6, j = tid & 63;
    float s = 0.0f, q = 0.0f;
    for (int i = blockIdx.x * 4 + wv; i < NN; i += gridDim.x * 4) {
        float v = h[i * CC + j];
        s += v;
        q += v * v;
    }
    ssum[wv][j] = s;
    ssq[wv][j] = q;
    __syncthreads();
    if (wv == 0) {
        s = ssum[0][j] + ssum[1][j] + ssum[2][j] + ssum[3][j];
        q = ssq[0][j] + ssq[1][j] + ssq[2][j] + ssq[3][j];
        atomicAdd(&stats[j], s);
        atomicAdd(&stats[CC + j], q);
    }
}

__global__ void k_bnfin(const float* gamma, const float* beta, float* stats) {
    int j = threadIdx.x;
    if (j < CC) {
        float mean = stats[j] / (float)NN;
        float var = stats[CC + j] / (float)NN - mean * mean;
        float sc = gamma[j] * rsqrtf(var + 1e-5f);
        stats[2 * CC + j] = sc;
        stats[3 * CC + j] = beta[j] - mean * sc;
    }
}

__global__ void k_starts(const int* __restrict__ batch, int* __restrict__ starts) {
    int i = blockIdx.x * blockDim.x + threadIdx.x;
    if (i >= NN) return;
    int b = batch[i];
    int bp = (i == 0) ? -1 : batch[i - 1];
    for (int g = bp + 1; g <= b; g++) starts[g] = i;
    if (i == NN - 1) {
        for (int g = b + 1; g <= GG; g++) starts[g] = NN;
    }
}

__global__ __launch_bounds__(256) void k_pool2(const float* __restrict__ h,
                                               const float* __restrict__ stats,
                                               const int* __restrict__ starts,
                                               float* __restrict__ out) {
    __shared__ float ssum[4][CC], smax[4][CC];
    int g = blockIdx.x;
    int s = starts[g], e = starts[g + 1];
    int tid = threadIdx.x, w = tid >> 6, j = tid & 63;
    float sc = stats[2 * CC + j], sh = stats[3 * CC + j];
    float sum = 0.0f, mx = -__builtin_inff();
    for (int i = s + w; i < e; i += 4) {
        float v = fmaf(h[i * CC + j], sc, sh);
        sum += v;
        mx = fmaxf(mx, v);
    }
    ssum[w][j] = sum;
    smax[w][j] = mx;
    __syncthreads();
    if (w == 0) {
        sum = ssum[0][j] + ssum[1][j] + ssum[2][j] + ssum[3][j];
        mx = fmaxf(fmaxf(smax[0][j], smax[1][j]), fmaxf(smax[2][j], smax[3][j]));
        int n = e - s;
        out[g * 2 * CC + j] = (n > 0) ? sum / (float)n : 0.0f;
        out[g * 2 * CC + CC + j] = mx;
    }
}

extern "C" void kernel_launch(void* const* d_in, const int* in_sizes, int n_in,
                              void* d_out, int out_size, void* d_ws, size_t ws_size,
                              hipStream_t stream) {
    const float* x = (const float*)d_in[0];
    const int* ei = (const int*)d_in[1];
    const float* ew = (const float*)d_in[2];
    const int* batch = (const int*)d_in[3];
    const float* W = (const float*)d_in[4];
    const float* b = (const float*)d_in[5];
    const float* a = (const float*)d_in[6];
    const float* gamma = (const float*)d_in[7];
    const float* beta = (const float*)d_in[8];
    float* out = (float*)d_out;

    float* ws = (float*)d_ws;
    // layout (floats): dinv 50048 | bin_cnt 256 | stats 256 | starts 256 | binbuf BINS*CAPB*2 | bufA | bufB
    float* dinv = ws;
    int* bin_cnt = (int*)(ws + 50048);
    float* stats = ws + 50048 + 256;
    int* starts = (int*)(stats + 256);
    int2* binbuf = (int2*)(starts + 256);
    float* bufA = (float*)(binbuf + (size_t)BINS * CAPB);
    float* bufB = bufA + NN * CC;

    dim3 blk(256);
    int gH = (NN + 3) / 4;

    k_zero<<<NB, blk, 0, stream>>>(bin_cnt, stats);
    k_binA<<<GA, blk, 0, stream>>>(ei, ew, bin_cnt, binbuf);
    k_degbin<<<BINS, blk, 0, stream>>>(bin_cnt, binbuf, dinv);
    k_starts<<<NB, blk, 0, stream>>>(batch, starts);

    k_hop_bin<<<BINS, dim3(1024), 0, stream>>>(x, dinv, bin_cnt, binbuf, bufA);
    k_hop_bin<<<BINS, dim3(1024), 0, stream>>>(bufA, dinv, bin_cnt, binbuf, bufB);

    k_linear<<<gH, blk, 0, stream>>>(bufB, W, b, a, bufA);
    k_stats<<<256, blk, 0, stream>>>(bufA, stats);
    k_bnfin<<<1, 64, 0, stream>>>(gamma, beta, stats);
    k_pool2<<<GG, blk, 0, stream>>>(bufA, stats, starts, out);
}

// Round 6
// 199.851 us; speedup vs baseline: 4.2974x; 4.2974x over previous
//
#include <hip/hip_runtime.h>
#include <math.h>

#define NN 50000
#define NE 800000
#define CC 64
#define GG 128
#define NB ((NN + 255) / 256)      // 196 node blocks
#define BINS ((NN + 255) / 256)    // 196 bins of 256 target nodes
#define CAPB 4608                  // bin capacity (mean 4096, +8 sigma)
#define EPB 2048                   // edges per binning block
#define GA ((NE + EPB - 1) / EPB)  // 391 binning blocks

// zero bin counters + stats
__global__ void k_zero(int* bin_cnt, float* stats) {
    int t = threadIdx.x;
    if (t < BINS) bin_cnt[t] = 0;
    if (t < 2 * CC) stats[t] = 0.0f;
}

// bin edges by target>>8; per-block LDS histogram, one global atomic per (block,bin)
__global__ __launch_bounds__(256) void k_binA(const int* __restrict__ ei,
                                              const float* __restrict__ w,
                                              int* __restrict__ bin_cnt,
                                              int2* __restrict__ binbuf) {
    __shared__ int hist[BINS], base[BINS], rank[BINS];
    int t = threadIdx.x;
    for (int b = t; b < BINS; b += 256) { hist[b] = 0; rank[b] = 0; }
    __syncthreads();
    int e0 = blockIdx.x * EPB;
    for (int i = t; i < EPB; i += 256) {
        int e = e0 + i;
        if (e < NE) atomicAdd(&hist[ei[NE + e] >> 8], 1);
    }
    __syncthreads();
    for (int b = t; b < BINS; b += 256)
        if (hist[b] > 0) base[b] = atomicAdd(&bin_cnt[b], hist[b]);
    __syncthreads();
    for (int i = t; i < EPB; i += 256) {
        int e = e0 + i;
        if (e >= NE) continue;
        int r = ei[e], c = ei[NE + e], b = c >> 8;
        int pos = base[b] + atomicAdd(&rank[b], 1);
        if (pos < CAPB)
            binbuf[(size_t)b * CAPB + pos] = make_int2(r | ((c & 255) << 16),
                                                       __float_as_int(w[e]));
    }
}

// one block per bin: LDS counting-sort by (target&255) -> per-node CSR (in place),
// fused weighted degree -> dinv. Zero device atomics.
__global__ __launch_bounds__(256) void k_csr(const int* __restrict__ bin_cnt,
                                             int2* __restrict__ binbuf,
                                             float* __restrict__ dinv,
                                             int* __restrict__ rps,
                                             int* __restrict__ rcnt) {
    __shared__ int2 ed[CAPB];
    __shared__ int hist[256], off[256], rank[256];
    __shared__ float degf[256];
    int g = blockIdx.x, t = threadIdx.x;
    int cnt = min(bin_cnt[g], CAPB);
    int2* bp = binbuf + (size_t)g * CAPB;
    hist[t] = 0; rank[t] = 0; degf[t] = 1.0f;   // deg starts at 1 (self-loop)
    __syncthreads();
    for (int e = t; e < cnt; e += 256) {
        int2 r = bp[e];
        ed[e] = r;
        int low = r.x >> 16;
        atomicAdd(&hist[low], 1);
        atomicAdd(&degf[low], __int_as_float(r.y));
    }
    __syncthreads();
    int v = hist[t];
    off[t] = v;
    __syncthreads();
    for (int o = 1; o < 256; o <<= 1) {        // inclusive scan
        int x = (t >= o) ? off[t - o] : 0;
        __syncthreads();
        off[t] += x;
        __syncthreads();
    }
    int node = g * 256 + t;
    if (node < NN) {
        dinv[node] = rsqrtf(degf[t]);
        rps[node] = g * CAPB + (off[t] - v);   // exclusive start
        rcnt[node] = v;
    }
    // place sorted (writes land in L2-hot dense region -> full-line writeback)
    for (int e = t; e < cnt; e += 256) {
        int2 r = ed[e];
        int low = r.x >> 16;
        int pos = (off[low] - hist[low]) + atomicAdd(&rank[low], 1);
        bp[pos] = make_int2(r.x & 0xffff, r.y);
    }
}

// wave per node, register accumulate; norm folded on the fly:
// out = dn * ( dn*in[node] + sum dinv[src]*w*in[src] )
__global__ __launch_bounds__(256) void k_hop2(const float* __restrict__ in,
                                              const float* __restrict__ dinv,
                                              const int* __restrict__ rps,
                                              const int* __restrict__ rcnt,
                                              const int2* __restrict__ csr,
                                              float* __restrict__ out) {
    int node = blockIdx.x * 4 + (threadIdx.x >> 6);
    int j = threadIdx.x & 63;
    if (node >= NN) return;
    float dn = dinv[node];
    float acc = dn * in[node * CC + j];
    int s = rps[node], n = rcnt[node];
    const int2* cp = csr + s;
#pragma unroll 4
    for (int p = 0; p < n; p++) {
        int2 rec = cp[p];
        float nw = dinv[rec.x] * __int_as_float(rec.y);
        acc = fmaf(nw, in[rec.x * CC + j], acc);
    }
    out[node * CC + j] = dn * acc;
}

// h @ W^T + b, then PReLU
__global__ __launch_bounds__(256) void k_linear(const float* __restrict__ h,
                                                const float* __restrict__ W,
                                                const float* __restrict__ b,
                                                const float* __restrict__ a,
                                                float* __restrict__ out) {
    __shared__ float Ws[CC * 65];
    __shared__ float hs[4][CC];
    int tid = threadIdx.x;
    for (int t = tid; t < CC * CC; t += 256) {
        int j = t >> 6, k = t & 63;
        Ws[j * 65 + k] = W[t];
    }
    int i0 = blockIdx.x * 4;
    {
        int node = i0 + (tid >> 6), k = tid & 63;
        hs[tid >> 6][k] = (node < NN) ? h[node * CC + k] : 0.0f;
    }
    __syncthreads();
    int node = i0 + (tid >> 6);
    int j = tid & 63;
    if (node >= NN) return;
    float acc = b[j];
    const float* hr = hs[tid >> 6];
#pragma unroll
    for (int k = 0; k < CC; k++) acc += hr[k] * Ws[j * 65 + k];
    float v = acc >= 0.0f ? acc : a[j] * acc;
    out[node * CC + j] = v;
}

// per-channel sum / sumsq over all N rows
__global__ __launch_bounds__(256) void k_stats(const float* __restrict__ h,
                                               float* __restrict__ stats) {
    __shared__ float ssum[4][CC], ssq[4][CC];
    int tid = threadIdx.x, wv = tid >> 6, j = tid & 63;
    float s = 0.0f, q = 0.0f;
    for (int i = blockIdx.x * 4 + wv; i < NN; i += gridDim.x * 4) {
        float v = h[i * CC + j];
        s += v;
        q += v * v;
    }
    ssum[wv][j] = s;
    ssq[wv][j] = q;
    __syncthreads();
    if (wv == 0) {
        s = ssum[0][j] + ssum[1][j] + ssum[2][j] + ssum[3][j];
        q = ssq[0][j] + ssq[1][j] + ssq[2][j] + ssq[3][j];
        atomicAdd(&stats[j], s);
        atomicAdd(&stats[CC + j], q);
    }
}

__global__ void k_bnfin(const float* gamma, const float* beta, float* stats) {
    int j = threadIdx.x;
    if (j < CC) {
        float mean = stats[j] / (float)NN;
        float var = stats[CC + j] / (float)NN - mean * mean;
        float sc = gamma[j] * rsqrtf(var + 1e-5f);
        stats[2 * CC + j] = sc;
        stats[3 * CC + j] = beta[j] - mean * sc;
    }
}

__global__ void k_starts(const int* __restrict__ batch, int* __restrict__ starts) {
    int i = blockIdx.x * blockDim.x + threadIdx.x;
    if (i >= NN) return;
    int b = batch[i];
    int bp = (i == 0) ? -1 : batch[i - 1];
    for (int g = bp + 1; g <= b; g++) starts[g] = i;
    if (i == NN - 1) {
        for (int g = b + 1; g <= GG; g++) starts[g] = NN;
    }
}

__global__ __launch_bounds__(256) void k_pool2(const float* __restrict__ h,
                                               const float* __restrict__ stats,
                                               const int* __restrict__ starts,
                                               float* __restrict__ out) {
    __shared__ float ssum[4][CC], smax[4][CC];
    int g = blockIdx.x;
    int s = starts[g], e = starts[g + 1];
    int tid = threadIdx.x, w = tid >> 6, j = tid & 63;
    float sc = stats[2 * CC + j], sh = stats[3 * CC + j];
    float sum = 0.0f, mx = -__builtin_inff();
    for (int i = s + w; i < e; i += 4) {
        float v = fmaf(h[i * CC + j], sc, sh);
        sum += v;
        mx = fmaxf(mx, v);
    }
    ssum[w][j] = sum;
    smax[w][j] = mx;
    __syncthreads();
    if (w == 0) {
        sum = ssum[0][j] + ssum[1][j] + ssum[2][j] + ssum[3][j];
        mx = fmaxf(fmaxf(smax[0][j], smax[1][j]), fmaxf(smax[2][j], smax[3][j]));
        int n = e - s;
        out[g * 2 * CC + j] = (n > 0) ? sum / (float)n : 0.0f;
        out[g * 2 * CC + CC + j] = mx;
    }
}

extern "C" void kernel_launch(void* const* d_in, const int* in_sizes, int n_in,
                              void* d_out, int out_size, void* d_ws, size_t ws_size,
                              hipStream_t stream) {
    const float* x = (const float*)d_in[0];
    const int* ei = (const int*)d_in[1];
    const float* ew = (const float*)d_in[2];
    const int* batch = (const int*)d_in[3];
    const float* W = (const float*)d_in[4];
    const float* b = (const float*)d_in[5];
    const float* a = (const float*)d_in[6];
    const float* gamma = (const float*)d_in[7];
    const float* beta = (const float*)d_in[8];
    float* out = (float*)d_out;

    float* ws = (float*)d_ws;
    // layout (floats): dinv 50048 | rps 50048 | rcnt 50048 | bin_cnt 256 | stats 256 |
    //                  starts 256 | binbuf BINS*CAPB*2 | bufA NN*CC | bufB NN*CC
    float* dinv = ws;
    int* rps = (int*)(ws + 50048);
    int* rcnt = (int*)(ws + 2 * 50048);
    int* bin_cnt = (int*)(ws + 3 * 50048);
    float* stats = ws + 3 * 50048 + 256;
    int* starts = (int*)(stats + 256);
    int2* binbuf = (int2*)(starts + 256);
    float* bufA = (float*)(binbuf + (size_t)BINS * CAPB);
    float* bufB = bufA + NN * CC;

    dim3 blk(256);
    int gH = (NN + 3) / 4;

    k_zero<<<1, blk, 0, stream>>>(bin_cnt, stats);
    k_binA<<<GA, blk, 0, stream>>>(ei, ew, bin_cnt, binbuf);
    k_csr<<<BINS, blk, 0, stream>>>(bin_cnt, binbuf, dinv, rps, rcnt);
    k_starts<<<NB, blk, 0, stream>>>(batch, starts);

    k_hop2<<<gH, blk, 0, stream>>>(x, dinv, rps, rcnt, binbuf, bufA);
    k_hop2<<<gH, blk, 0, stream>>>(bufA, dinv, rps, rcnt, binbuf, bufB);

    k_linear<<<gH, blk, 0, stream>>>(bufB, W, b, a, bufA);
    k_stats<<<256, blk, 0, stream>>>(bufA, stats);
    k_bnfin<<<1, 64, 0, stream>>>(gamma, beta, stats);
    k_pool2<<<GG, blk, 0, stream>>>(bufA, stats, starts, out);
}